// Round 4
// baseline (364.033 us; speedup 1.0000x reference)
//
#include <hip/hip_runtime.h>

// OSNAP sketch: out[n,f] = sum_d x[n,d] * P[f,d]
// x: [16384,4096] f32. P: [8192,4096] f32, exactly 4 nonzeros (+-0.5) per COLUMN.
// Structure extracted per launch into d_ws, then a fixed-4-entry gather kernel.
// Gather: each block stages 4 x-rows (pre-scaled by 0.5) interleaved in LDS;
// each thread owns 4 consecutive f -> dwordx4 stores, 16-deep LDS-read MLP.

#define D_IN    4096
#define D_FEAT  8192
#define N_TOT   16384
#define CAP     16        // per-row clamp (P(Poisson(2) >= 16) ~ 4e-10 per row)
#define NR      4         // x-rows per gather block
#define FPT     4         // output features per thread in gather
#define OVF_CAP 16384

typedef float f32x4 __attribute__((ext_vector_type(4)));

// ---------------- ws layout (bytes, NO overlaps) ----------------
// 0        col_f    int  [D_IN*4]      65536
// 65536    col_v    float[D_IN*4]      65536   -> 131072
// 131072   col_cnt  int  [D_IN]        16384   -> 147456
// 147456   row_cnt  int  [D_FEAT]      32768   -> 180224
// 180224   row_ent  int2 [D_FEAT*CAP]  1048576 -> 1228800   (.x=d, .y=bits(val))
// 1228800  ent4     int4 [D_FEAT]      131072  -> 1359872   (4 packed entries/row)
// 1359872  ovf_desc int  [D_FEAT]      32768   -> 1392640   ((start<<5)|extra)
// 1392640  ovf_ents int  [OVF_CAP]     65536   -> 1458176
// 1458176  ovf_base int  [1]           4       -> 1458180
// total ~1.46 MB

__global__ void k_zero(int* __restrict__ col_cnt, int* __restrict__ row_cnt,
                       int* __restrict__ ovf_base) {
    int t = blockIdx.x * blockDim.x + threadIdx.x;
    if (t < D_IN)   col_cnt[t] = 0;
    if (t < D_FEAT) row_cnt[t] = 0;
    if (t == 0)     ovf_base[0] = 0;
}

// Full-BW streaming scan of P (128MB): append each column's 4 nonzeros.
__global__ void k_scan(const f32x4* __restrict__ p4,
                       int* __restrict__ col_cnt,
                       int* __restrict__ col_f,
                       float* __restrict__ col_v) {
    const long total = (long)D_FEAT * D_IN / 4;
    for (long q = (long)blockIdx.x * blockDim.x + threadIdx.x; q < total;
         q += (long)gridDim.x * blockDim.x) {
        f32x4 v = __builtin_nontemporal_load(&p4[q]);
        long base = q * 4;
        float vals[4] = {v.x, v.y, v.z, v.w};
        #pragma unroll
        for (int c = 0; c < 4; ++c) {
            if (vals[c] != 0.0f) {
                long i = base + c;
                int f = (int)(i >> 12);          // / D_IN
                int d = (int)(i & (D_IN - 1));   // % D_IN
                int slot = atomicAdd(&col_cnt[d], 1);
                if (slot < 4) {
                    col_f[d * 4 + slot] = f;
                    col_v[d * 4 + slot] = vals[c];
                }
            }
        }
    }
}

// Bin column entries into per-row lists (order canonicalized by k_sortpack).
__global__ void k_bin(const int* __restrict__ col_f, const float* __restrict__ col_v,
                      int* __restrict__ row_cnt, int2* __restrict__ row_ent) {
    int e = blockIdx.x * blockDim.x + threadIdx.x;
    if (e >= D_IN * 4) return;
    int d = e >> 2;
    int f = col_f[e];
    float v = col_v[e];
    int slot = atomicAdd(&row_cnt[f], 1);
    if (slot < CAP) row_ent[f * CAP + slot] = make_int2(d, __float_as_int(v));
}

// Per row f: sort entries by d (distinct -> deterministic values), pack first 4
// into int4 (entry = d*16 | sign<<31; dummy = D_IN*16 -> zero LDS slot; bit30 of
// .w = overflow flag), extras -> atomically-allocated compact slab. Overflow
// start offsets vary run-to-run but per-row entry ORDER doesn't, so output
// values are bitwise deterministic.
__global__ void k_sortpack(const int* __restrict__ row_cnt, int2* __restrict__ row_ent,
                           int4* __restrict__ ent4, int* __restrict__ ovf_desc,
                           int* __restrict__ ovf_ents, int* __restrict__ ovf_base) {
    int f = blockIdx.x * blockDim.x + threadIdx.x;
    if (f >= D_FEAT) return;
    int cnt = row_cnt[f];
    if (cnt > CAP) cnt = CAP;
    // insertion sort in global memory (L2-resident, tiny)
    for (int a = 1; a < cnt; ++a) {
        int2 key = row_ent[f * CAP + a];
        int b = a - 1;
        while (b >= 0) {
            int2 cur = row_ent[f * CAP + b];
            if (cur.x <= key.x) break;
            row_ent[f * CAP + b + 1] = cur;
            --b;
        }
        row_ent[f * CAP + b + 1] = key;
    }
    int e[4];
    #pragma unroll
    for (int j = 0; j < 4; ++j) {
        if (j < cnt) {
            int2 ev = row_ent[f * CAP + j];
            e[j] = (ev.x * 16) | (int)((unsigned)ev.y & 0x80000000u);
        } else {
            e[j] = D_IN * 16;   // dummy -> zeroed LDS slot
        }
    }
    int extra = (cnt > 4) ? (cnt - 4) : 0;
    int start = 0;
    if (extra) {
        start = atomicAdd(ovf_base, extra);
        if (start < 0) start = 0;
        if (start > OVF_CAP - CAP) start = OVF_CAP - CAP;   // capacity guard
        for (int j = 0; j < extra; ++j) {
            int2 ev = row_ent[f * CAP + 4 + j];
            ovf_ents[start + j] = (ev.x * 16) | (int)((unsigned)ev.y & 0x80000000u);
        }
        e[3] |= 0x40000000;
    }
    ovf_desc[f] = (start << 5) | extra;
    ent4[f] = make_int4(e[0], e[1], e[2], e[3]);
}

// Main gather.
__global__ __launch_bounds__(512, 4) void k_gather(const float* __restrict__ x,
                                                   const int4* __restrict__ ent4,
                                                   const int* __restrict__ ovf_desc,
                                                   const int* __restrict__ ovf_ents,
                                                   float* __restrict__ out) {
    __shared__ float xs[D_IN * NR + 4];   // +4: zero slot for dummy entries
    const int n0 = blockIdx.x * NR;
    const int tid = threadIdx.x;

    // Stage rows n0..n0+3 interleaved and PRE-SCALED: xs[d*4+r] = 0.5*x[n0+r][d].
    // LDS writes sequential (conflict-free); global reads: 4x 64B segs per wave.
    for (int idx = tid; idx < D_IN * NR; idx += 512) {
        int r = idx & (NR - 1);
        int d = idx >> 2;
        xs[idx] = 0.5f * __builtin_nontemporal_load(&x[(size_t)(n0 + r) * D_IN + d]);
    }
    if (tid < 4) xs[D_IN * NR + tid] = 0.f;
    __syncthreads();

    const char* xsb = (const char*)xs;
    float* o0 = out + (size_t)n0 * D_FEAT;
    float* o1 = o0 + D_FEAT;
    float* o2 = o1 + D_FEAT;
    float* o3 = o2 + D_FEAT;

    // acc aKR: K = f-lane within quad, R = x-row.  ENT adds one entry to row accs.
    #define ENT(EE, A0, A1, A2, A3) { \
        f32x4 xv = *(const f32x4*)(xsb + ((EE) & 0x1FFF0)); \
        unsigned sg = (unsigned)(EE) & 0x80000000u; \
        A0 += __uint_as_float(__float_as_uint(xv.x) ^ sg); \
        A1 += __uint_as_float(__float_as_uint(xv.y) ^ sg); \
        A2 += __uint_as_float(__float_as_uint(xv.z) ^ sg); \
        A3 += __uint_as_float(__float_as_uint(xv.w) ^ sg); }

    #pragma unroll 1
    for (int p = 0; p < D_FEAT / (512 * FPT); ++p) {
        const int fb = p * (512 * FPT) + tid * FPT;
        int4 e0 = ent4[fb + 0];
        int4 e1 = ent4[fb + 1];
        int4 e2 = ent4[fb + 2];
        int4 e3 = ent4[fb + 3];
        float a00 = 0.f, a01 = 0.f, a02 = 0.f, a03 = 0.f;
        float a10 = 0.f, a11 = 0.f, a12 = 0.f, a13 = 0.f;
        float a20 = 0.f, a21 = 0.f, a22 = 0.f, a23 = 0.f;
        float a30 = 0.f, a31 = 0.f, a32 = 0.f, a33 = 0.f;
        ENT(e0.x, a00, a01, a02, a03) ENT(e0.y, a00, a01, a02, a03)
        ENT(e0.z, a00, a01, a02, a03) ENT(e0.w, a00, a01, a02, a03)
        ENT(e1.x, a10, a11, a12, a13) ENT(e1.y, a10, a11, a12, a13)
        ENT(e1.z, a10, a11, a12, a13) ENT(e1.w, a10, a11, a12, a13)
        ENT(e2.x, a20, a21, a22, a23) ENT(e2.y, a20, a21, a22, a23)
        ENT(e2.z, a20, a21, a22, a23) ENT(e2.w, a20, a21, a22, a23)
        ENT(e3.x, a30, a31, a32, a33) ENT(e3.y, a30, a31, a32, a33)
        ENT(e3.z, a30, a31, a32, a33) ENT(e3.w, a30, a31, a32, a33)

        if ((e0.w | e1.w | e2.w | e3.w) & 0x40000000) {   // rare overflow tails
            if (e0.w & 0x40000000) {
                int od = ovf_desc[fb + 0]; int ex = od & 31;
                const int* oe = ovf_ents + (od >> 5);
                for (int j = 0; j < ex; ++j) { int ee = oe[j]; ENT(ee, a00, a01, a02, a03) }
            }
            if (e1.w & 0x40000000) {
                int od = ovf_desc[fb + 1]; int ex = od & 31;
                const int* oe = ovf_ents + (od >> 5);
                for (int j = 0; j < ex; ++j) { int ee = oe[j]; ENT(ee, a10, a11, a12, a13) }
            }
            if (e2.w & 0x40000000) {
                int od = ovf_desc[fb + 2]; int ex = od & 31;
                const int* oe = ovf_ents + (od >> 5);
                for (int j = 0; j < ex; ++j) { int ee = oe[j]; ENT(ee, a20, a21, a22, a23) }
            }
            if (e3.w & 0x40000000) {
                int od = ovf_desc[fb + 3]; int ex = od & 31;
                const int* oe = ovf_ents + (od >> 5);
                for (int j = 0; j < ex; ++j) { int ee = oe[j]; ENT(ee, a30, a31, a32, a33) }
            }
        }
        f32x4 r0 = {a00, a10, a20, a30};
        f32x4 r1 = {a01, a11, a21, a31};
        f32x4 r2 = {a02, a12, a22, a32};
        f32x4 r3 = {a03, a13, a23, a33};
        __builtin_nontemporal_store(r0, (f32x4*)(o0 + fb));
        __builtin_nontemporal_store(r1, (f32x4*)(o1 + fb));
        __builtin_nontemporal_store(r2, (f32x4*)(o2 + fb));
        __builtin_nontemporal_store(r3, (f32x4*)(o3 + fb));
    }
    #undef ENT
}

extern "C" void kernel_launch(void* const* d_in, const int* in_sizes, int n_in,
                              void* d_out, int out_size, void* d_ws, size_t ws_size,
                              hipStream_t stream) {
    const float* x = (const float*)d_in[0];
    const float* P = (const float*)d_in[1];
    float* out = (float*)d_out;

    char* ws = (char*)d_ws;
    int*   col_f    = (int*)  (ws + 0);
    float* col_v    = (float*)(ws + 65536);
    int*   col_cnt  = (int*)  (ws + 131072);
    int*   row_cnt  = (int*)  (ws + 147456);
    int2*  row_ent  = (int2*) (ws + 180224);
    int4*  ent4     = (int4*) (ws + 1228800);
    int*   ovf_desc = (int*)  (ws + 1359872);
    int*   ovf_ents = (int*)  (ws + 1392640);
    int*   ovf_base = (int*)  (ws + 1458176);

    k_zero    <<<(D_FEAT + 255) / 256, 256, 0, stream>>>(col_cnt, row_cnt, ovf_base);
    k_scan    <<<2048, 256, 0, stream>>>((const f32x4*)P, col_cnt, col_f, col_v);
    k_bin     <<<(D_IN * 4 + 255) / 256, 256, 0, stream>>>(col_f, col_v, row_cnt, row_ent);
    k_sortpack<<<(D_FEAT + 255) / 256, 256, 0, stream>>>(row_cnt, row_ent, ent4,
                                                         ovf_desc, ovf_ents, ovf_base);
    k_gather  <<<N_TOT / NR, 512, 0, stream>>>(x, ent4, ovf_desc, ovf_ents, out);
}

// Round 5
// 207.901 us; speedup vs baseline: 1.7510x; 1.7510x over previous
//
#include <hip/hip_runtime.h>

// OSNAP sketch: out[n,f] = sum_d x[n,d] * P[f,d]
// x: [16384,4096] f32. P: [8192,4096] f32, exactly 4 nonzeros (+-0.5) per COLUMN.
// Structure extracted per launch into d_ws, then a fixed-4-entry gather kernel.
// Gather v5: row-major padded LDS (conflict-free b128 staging writes, coalesced
// float4 global loads), 4x ds_read_b32 per entry, 1024-thr blocks (32 waves/CU).

#define D_IN    4096
#define D_FEAT  8192
#define N_TOT   16384
#define CAP     16        // per-row clamp (P(Poisson(2) >= 16) ~ 4e-10 per row)
#define NR      4         // x-rows per gather block
#define FPT     4         // output features per thread per iteration
#define PADW    8         // pad words per LDS row (also the zero slot for dummies)
#define ROWW    (D_IN + PADW)   // 4104 words
#define OVF_CAP 16384

typedef float f32x4 __attribute__((ext_vector_type(4)));

// ---------------- ws layout (bytes, NO overlaps) ----------------
// 0        col_f    int  [D_IN*4]      65536
// 65536    col_v    float[D_IN*4]      65536   -> 131072
// 131072   col_cnt  int  [D_IN]        16384   -> 147456
// 147456   row_cnt  int  [D_FEAT]      32768   -> 180224
// 180224   row_ent  int2 [D_FEAT*CAP]  1048576 -> 1228800   (.x=d, .y=bits(val))
// 1228800  ent4     int4 [D_FEAT]      131072  -> 1359872   (4 packed entries/row)
// 1359872  ovf_desc int  [D_FEAT]      32768   -> 1392640   ((start<<5)|extra)
// 1392640  ovf_ents int  [OVF_CAP]     65536   -> 1458176
// 1458176  ovf_base int  [1]           4       -> 1458180

__global__ void k_zero(int* __restrict__ col_cnt, int* __restrict__ row_cnt,
                       int* __restrict__ ovf_base) {
    int t = blockIdx.x * blockDim.x + threadIdx.x;
    if (t < D_IN)   col_cnt[t] = 0;
    if (t < D_FEAT) row_cnt[t] = 0;
    if (t == 0)     ovf_base[0] = 0;
}

// Full-BW streaming scan of P (128MB): append each column's 4 nonzeros.
__global__ void k_scan(const f32x4* __restrict__ p4,
                       int* __restrict__ col_cnt,
                       int* __restrict__ col_f,
                       float* __restrict__ col_v) {
    const long total = (long)D_FEAT * D_IN / 4;
    for (long q = (long)blockIdx.x * blockDim.x + threadIdx.x; q < total;
         q += (long)gridDim.x * blockDim.x) {
        f32x4 v = __builtin_nontemporal_load(&p4[q]);
        long base = q * 4;
        float vals[4] = {v.x, v.y, v.z, v.w};
        #pragma unroll
        for (int c = 0; c < 4; ++c) {
            if (vals[c] != 0.0f) {
                long i = base + c;
                int f = (int)(i >> 12);          // / D_IN
                int d = (int)(i & (D_IN - 1));   // % D_IN
                int slot = atomicAdd(&col_cnt[d], 1);
                if (slot < 4) {
                    col_f[d * 4 + slot] = f;
                    col_v[d * 4 + slot] = vals[c];
                }
            }
        }
    }
}

// Bin column entries into per-row lists (order canonicalized by k_sortpack).
__global__ void k_bin(const int* __restrict__ col_f, const float* __restrict__ col_v,
                      int* __restrict__ row_cnt, int2* __restrict__ row_ent) {
    int e = blockIdx.x * blockDim.x + threadIdx.x;
    if (e >= D_IN * 4) return;
    int d = e >> 2;
    int f = col_f[e];
    float v = col_v[e];
    int slot = atomicAdd(&row_cnt[f], 1);
    if (slot < CAP) row_ent[f * CAP + slot] = make_int2(d, __float_as_int(v));
}

// Per row f: sort entries by d (distinct -> deterministic), pack first 4 into
// int4 (entry = d*4 | sign<<31; dummy = D_IN*4 -> zeroed pad word; bit30 of .w =
// overflow flag), extras -> atomically-allocated compact slab. Start offsets
// vary run-to-run but per-row entry ORDER doesn't -> bitwise-deterministic out.
__global__ void k_sortpack(const int* __restrict__ row_cnt, int2* __restrict__ row_ent,
                           int4* __restrict__ ent4, int* __restrict__ ovf_desc,
                           int* __restrict__ ovf_ents, int* __restrict__ ovf_base) {
    int f = blockIdx.x * blockDim.x + threadIdx.x;
    if (f >= D_FEAT) return;
    int cnt = row_cnt[f];
    if (cnt > CAP) cnt = CAP;
    for (int a = 1; a < cnt; ++a) {
        int2 key = row_ent[f * CAP + a];
        int b = a - 1;
        while (b >= 0) {
            int2 cur = row_ent[f * CAP + b];
            if (cur.x <= key.x) break;
            row_ent[f * CAP + b + 1] = cur;
            --b;
        }
        row_ent[f * CAP + b + 1] = key;
    }
    int e[4];
    #pragma unroll
    for (int j = 0; j < 4; ++j) {
        if (j < cnt) {
            int2 ev = row_ent[f * CAP + j];
            e[j] = (ev.x * 4) | (int)((unsigned)ev.y & 0x80000000u);
        } else {
            e[j] = D_IN * 4;   // dummy -> zeroed pad word
        }
    }
    int extra = (cnt > 4) ? (cnt - 4) : 0;
    int start = 0;
    if (extra) {
        start = atomicAdd(ovf_base, extra);
        if (start < 0) start = 0;
        if (start > OVF_CAP - CAP) start = OVF_CAP - CAP;   // capacity guard
        for (int j = 0; j < extra; ++j) {
            int2 ev = row_ent[f * CAP + 4 + j];
            ovf_ents[start + j] = (ev.x * 4) | (int)((unsigned)ev.y & 0x80000000u);
        }
        e[3] |= 0x40000000;
    }
    ovf_desc[f] = (start << 5) | extra;
    ent4[f] = make_int4(e[0], e[1], e[2], e[3]);
}

// Main gather.
__global__ __launch_bounds__(1024, 8) void k_gather(const float* __restrict__ x,
                                                    const int4* __restrict__ ent4,
                                                    const int* __restrict__ ovf_desc,
                                                    const int* __restrict__ ovf_ents,
                                                    float* __restrict__ out) {
    __shared__ float xs[NR * ROWW];   // 65,664 B -> 2 blocks/CU
    const int n0 = blockIdx.x * NR;
    const int tid = threadIdx.x;

    // Stage rows n0..n0+3 row-major, pre-scaled by 0.5.
    // float4 loads: 16 B/lane coalesced. b128 LDS writes: 16 B lane-stride =
    // 8 words/bank = conflict-free.
    const f32x4* xr4 = (const f32x4*)x;
    #pragma unroll
    for (int r = 0; r < NR; ++r) {
        f32x4 v = __builtin_nontemporal_load(&xr4[((size_t)(n0 + r) << 10) + tid]);
        v *= 0.5f;
        *(f32x4*)&xs[r * ROWW + tid * 4] = v;
    }
    // zero the pad words (dummy entries read word D_IN of each row)
    if (tid < NR * PADW) xs[(tid >> 3) * ROWW + D_IN + (tid & 7)] = 0.f;
    __syncthreads();

    const char* xsb  = (const char*)xs;                 // rows 0,1 (imm 0 / 16416)
    const char* xsb2 = (const char*)(xs + 2 * ROWW);    // rows 2,3
    float* o0 = out + (size_t)n0 * D_FEAT;
    float* o1 = o0 + D_FEAT;
    float* o2 = o1 + D_FEAT;
    float* o3 = o2 + D_FEAT;

    // ENT adds one entry (packed d*4 | sign<<31) to the 4 row-accumulators.
    #define ENT(EE, A0, A1, A2, A3) { \
        int off = (EE) & 0x7FFC; \
        float v0 = *(const float*)(xsb  + off); \
        float v1 = *(const float*)(xsb  + off + ROWW * 4); \
        float v2 = *(const float*)(xsb2 + off); \
        float v3 = *(const float*)(xsb2 + off + ROWW * 4); \
        unsigned sg = (unsigned)(EE) & 0x80000000u; \
        A0 += __uint_as_float(__float_as_uint(v0) ^ sg); \
        A1 += __uint_as_float(__float_as_uint(v1) ^ sg); \
        A2 += __uint_as_float(__float_as_uint(v2) ^ sg); \
        A3 += __uint_as_float(__float_as_uint(v3) ^ sg); }

    #pragma unroll 1
    for (int p = 0; p < D_FEAT / (1024 * FPT); ++p) {
        const int fb = p * (1024 * FPT) + tid * FPT;
        int4 e0 = ent4[fb + 0];
        int4 e1 = ent4[fb + 1];
        int4 e2 = ent4[fb + 2];
        int4 e3 = ent4[fb + 3];
        float a00 = 0.f, a01 = 0.f, a02 = 0.f, a03 = 0.f;
        float a10 = 0.f, a11 = 0.f, a12 = 0.f, a13 = 0.f;
        float a20 = 0.f, a21 = 0.f, a22 = 0.f, a23 = 0.f;
        float a30 = 0.f, a31 = 0.f, a32 = 0.f, a33 = 0.f;
        ENT(e0.x, a00, a01, a02, a03) ENT(e0.y, a00, a01, a02, a03)
        ENT(e0.z, a00, a01, a02, a03) ENT(e0.w, a00, a01, a02, a03)
        ENT(e1.x, a10, a11, a12, a13) ENT(e1.y, a10, a11, a12, a13)
        ENT(e1.z, a10, a11, a12, a13) ENT(e1.w, a10, a11, a12, a13)
        ENT(e2.x, a20, a21, a22, a23) ENT(e2.y, a20, a21, a22, a23)
        ENT(e2.z, a20, a21, a22, a23) ENT(e2.w, a20, a21, a22, a23)
        ENT(e3.x, a30, a31, a32, a33) ENT(e3.y, a30, a31, a32, a33)
        ENT(e3.z, a30, a31, a32, a33) ENT(e3.w, a30, a31, a32, a33)

        if ((e0.w | e1.w | e2.w | e3.w) & 0x40000000) {   // rare overflow tails
            if (e0.w & 0x40000000) {
                int od = ovf_desc[fb + 0]; int ex = od & 31;
                const int* oe = ovf_ents + (od >> 5);
                for (int j = 0; j < ex; ++j) { int ee = oe[j]; ENT(ee, a00, a01, a02, a03) }
            }
            if (e1.w & 0x40000000) {
                int od = ovf_desc[fb + 1]; int ex = od & 31;
                const int* oe = ovf_ents + (od >> 5);
                for (int j = 0; j < ex; ++j) { int ee = oe[j]; ENT(ee, a10, a11, a12, a13) }
            }
            if (e2.w & 0x40000000) {
                int od = ovf_desc[fb + 2]; int ex = od & 31;
                const int* oe = ovf_ents + (od >> 5);
                for (int j = 0; j < ex; ++j) { int ee = oe[j]; ENT(ee, a20, a21, a22, a23) }
            }
            if (e3.w & 0x40000000) {
                int od = ovf_desc[fb + 3]; int ex = od & 31;
                const int* oe = ovf_ents + (od >> 5);
                for (int j = 0; j < ex; ++j) { int ee = oe[j]; ENT(ee, a30, a31, a32, a33) }
            }
        }
        f32x4 r0 = {a00, a10, a20, a30};
        f32x4 r1 = {a01, a11, a21, a31};
        f32x4 r2 = {a02, a12, a22, a32};
        f32x4 r3 = {a03, a13, a23, a33};
        __builtin_nontemporal_store(r0, (f32x4*)(o0 + fb));
        __builtin_nontemporal_store(r1, (f32x4*)(o1 + fb));
        __builtin_nontemporal_store(r2, (f32x4*)(o2 + fb));
        __builtin_nontemporal_store(r3, (f32x4*)(o3 + fb));
    }
    #undef ENT
}

extern "C" void kernel_launch(void* const* d_in, const int* in_sizes, int n_in,
                              void* d_out, int out_size, void* d_ws, size_t ws_size,
                              hipStream_t stream) {
    const float* x = (const float*)d_in[0];
    const float* P = (const float*)d_in[1];
    float* out = (float*)d_out;

    char* ws = (char*)d_ws;
    int*   col_f    = (int*)  (ws + 0);
    float* col_v    = (float*)(ws + 65536);
    int*   col_cnt  = (int*)  (ws + 131072);
    int*   row_cnt  = (int*)  (ws + 147456);
    int2*  row_ent  = (int2*) (ws + 180224);
    int4*  ent4     = (int4*) (ws + 1228800);
    int*   ovf_desc = (int*)  (ws + 1359872);
    int*   ovf_ents = (int*)  (ws + 1392640);
    int*   ovf_base = (int*)  (ws + 1458176);

    k_zero    <<<(D_FEAT + 255) / 256, 256, 0, stream>>>(col_cnt, row_cnt, ovf_base);
    k_scan    <<<2048, 256, 0, stream>>>((const f32x4*)P, col_cnt, col_f, col_v);
    k_bin     <<<(D_IN * 4 + 255) / 256, 256, 0, stream>>>(col_f, col_v, row_cnt, row_ent);
    k_sortpack<<<(D_FEAT + 255) / 256, 256, 0, stream>>>(row_cnt, row_ent, ent4,
                                                         ovf_desc, ovf_ents, ovf_base);
    k_gather  <<<N_TOT / NR, 1024, 0, stream>>>(x, ent4, ovf_desc, ovf_ents, out);
}